// Round 4
// baseline (275.429 us; speedup 1.0000x reference)
//
#include <hip/hip_runtime.h>
#include <hip/hip_bf16.h>

typedef short bf16x8 __attribute__((ext_vector_type(8)));
typedef float f32x4 __attribute__((ext_vector_type(4)));
typedef unsigned short u16;
typedef u16 u16x8 __attribute__((ext_vector_type(8)));

#define MFMA16(a, b, c) __builtin_amdgcn_mfma_f32_16x16x32_bf16(a, b, c, 0, 0, 0)

// B=2, T=1024, C=1024, H=16, HD=64.
// Inputs fp32; outputs fp32: y [2M], a [32M].
// d_ws (u16 elems): q[2M] k[2M] vt[2M] ao[2M] Qb[2M] Kb[2M] Vb[2M]
//                   Wqb[1M] Wkb[1M] Wvb[1M] Wpb[1M]  = 18M u16 = 36 MB.

__device__ __forceinline__ u16 f2bf(float f) {
    unsigned u = __builtin_bit_cast(unsigned, f);
    unsigned r = (u + 0x7FFFu + ((u >> 16) & 1u)) >> 16;
    return (u16)r;
}

// ---------------------------------------------------------------------------
// cvt_bf16 prepass: fp32 -> bf16 (RNE) for all GEMM operands, once.
// grid (1024, 7); z: 0=Q 1=K 2=V 3=Wq 4=Wk 5=Wv 6=Wp.
// ---------------------------------------------------------------------------
__global__ __launch_bounds__(256) void cvt_bf16(
    const float* __restrict__ Q, const float* __restrict__ K, const float* __restrict__ V,
    const float* __restrict__ Wq, const float* __restrict__ Wk, const float* __restrict__ Wv,
    const float* __restrict__ Wp,
    u16* __restrict__ Qb, u16* __restrict__ Kb, u16* __restrict__ Vb,
    u16* __restrict__ Wqb, u16* __restrict__ Wkb, u16* __restrict__ Wvb,
    u16* __restrict__ Wpb) {
    const int z = blockIdx.y;
    const float* src;
    u16* dst;
    int n;
    switch (z) {
        case 0: src = Q;  dst = Qb;  n = 1 << 21; break;
        case 1: src = K;  dst = Kb;  n = 1 << 21; break;
        case 2: src = V;  dst = Vb;  n = 1 << 21; break;
        case 3: src = Wq; dst = Wqb; n = 1 << 20; break;
        case 4: src = Wk; dst = Wkb; n = 1 << 20; break;
        case 5: src = Wv; dst = Wvb; n = 1 << 20; break;
        default: src = Wp; dst = Wpb; n = 1 << 20; break;
    }
    const int i = (blockIdx.x * 256 + threadIdx.x) * 8;
    if (i >= n) return;
    float4 f0 = *(const float4*)(src + i);
    float4 f1 = *(const float4*)(src + i + 4);
    u16x8 t;
    t[0] = f2bf(f0.x); t[1] = f2bf(f0.y); t[2] = f2bf(f0.z); t[3] = f2bf(f0.w);
    t[4] = f2bf(f1.x); t[5] = f2bf(f1.y); t[6] = f2bf(f1.z); t[7] = f2bf(f1.w);
    *(u16x8*)(dst + i) = t;
}

// ---------------------------------------------------------------------------
// m97-style bt-GEMM: out = A(Mx1024) @ W(1024x1024)^T + bias.
// Linear LDS [row][64], staged via global_load_lds width=16 (no VALU staging).
// BM x 64 tile, BK=64, 4 waves. BM=128 for proj_qkv, BM=64 for proj_out.
// mode 0: [b,h,t,d]; mode 1: [b,h,d,t]; mode 2: row-major (fp32 y).
// ---------------------------------------------------------------------------
template <int BM, bool OF32>
__device__ inline void gemm_body(const u16* __restrict__ A,
                                 const u16* __restrict__ W,
                                 const float* __restrict__ bias,
                                 void* __restrict__ outp, int mode) {
    __shared__ u16 As[BM * 64];   // [row][64] linear
    __shared__ u16 Bs[64 * 64];   // [row][64] linear

    const int tid = threadIdx.x;
    const int wave = tid >> 6, lane = tid & 63;
    const int quad = lane >> 4, l16 = lane & 15;
    constexpr int WM = BM / 2;    // wave tile rows
    constexpr int MI = WM / 16;   // m-frags per wave
    const int wm = (wave >> 1) * WM;
    const int wn = (wave & 1) * 32;
    const int m0 = blockIdx.y * BM;
    const int n0 = blockIdx.x * 64;

    f32x4 acc[MI][2] = {};

    const int lrow = lane >> 3;
    const int lseg = lane & 7;
    const u16* Ag = A + (size_t)(m0 + wave * 8 + lrow) * 1024 + lseg * 8;
    const u16* Wg = W + (size_t)(n0 + wave * 8 + lrow) * 1024 + lseg * 8;
    u16* AsBase = As + wave * 8 * 64;
    u16* BsBase = Bs + wave * 8 * 64;

    for (int kt = 0; kt < 16; ++kt) {
        const int k0 = kt * 64;
        __syncthreads();
#pragma unroll
        for (int rr = 0; rr < BM / 32; ++rr)
            __builtin_amdgcn_global_load_lds(
                (const __attribute__((address_space(1))) void*)(Ag + (size_t)rr * 32 * 1024 + k0),
                (__attribute__((address_space(3))) void*)(AsBase + rr * 32 * 64), 16, 0, 0);
#pragma unroll
        for (int rr = 0; rr < 2; ++rr)
            __builtin_amdgcn_global_load_lds(
                (const __attribute__((address_space(1))) void*)(Wg + (size_t)rr * 32 * 1024 + k0),
                (__attribute__((address_space(3))) void*)(BsBase + rr * 32 * 64), 16, 0, 0);
        __syncthreads();
#pragma unroll
        for (int ks = 0; ks < 2; ++ks) {
            bf16x8 af[MI], bfr[2];
#pragma unroll
            for (int mi = 0; mi < MI; ++mi)
                af[mi] = *(const bf16x8*)(As + (wm + mi * 16 + l16) * 64 + ks * 32 + quad * 8);
#pragma unroll
            for (int ni = 0; ni < 2; ++ni)
                bfr[ni] = *(const bf16x8*)(Bs + (wn + ni * 16 + l16) * 64 + ks * 32 + quad * 8);
#pragma unroll
            for (int mi = 0; mi < MI; ++mi)
#pragma unroll
                for (int ni = 0; ni < 2; ++ni)
                    acc[mi][ni] = MFMA16(af[mi], bfr[ni], acc[mi][ni]);
        }
    }

#pragma unroll
    for (int ni = 0; ni < 2; ++ni) {
        const int n = n0 + wn + ni * 16 + l16;
        const float bv = bias[n];
#pragma unroll
        for (int mi = 0; mi < MI; ++mi) {
#pragma unroll
            for (int r = 0; r < 4; ++r) {
                const int m = m0 + wm + mi * 16 + quad * 4 + r;
                const float val = acc[mi][ni][r] + bv;
                size_t idx;
                if (mode == 0) {
                    int b = m >> 10, t = m & 1023, h = n >> 6, d = n & 63;
                    idx = ((size_t)((b * 16 + h) * 1024 + t)) * 64 + d;
                } else if (mode == 1) {
                    int b = m >> 10, t = m & 1023, h = n >> 6, d = n & 63;
                    idx = ((size_t)((b * 16 + h) * 64 + d)) * 1024 + t;
                } else {
                    idx = (size_t)m * 1024 + n;
                }
                if (OF32) ((float*)outp)[idx] = val;
                else      ((u16*)outp)[idx] = f2bf(val);
            }
        }
    }
}

__global__ __launch_bounds__(256) void proj_qkv(
    const u16* __restrict__ Qb, const u16* __restrict__ Kb, const u16* __restrict__ Vb,
    const u16* __restrict__ Wqb, const u16* __restrict__ Wkb, const u16* __restrict__ Wvb,
    const float* __restrict__ bq, const float* __restrict__ bk, const float* __restrict__ bv,
    u16* __restrict__ q_ws, u16* __restrict__ k_ws, u16* __restrict__ vt_ws) {
    const int z = blockIdx.z;
    const u16* A = (z == 0) ? Qb : (z == 1) ? Kb : Vb;
    const u16* W = (z == 0) ? Wqb : (z == 1) ? Wkb : Wvb;
    const float* bias = (z == 0) ? bq : (z == 1) ? bk : bv;
    u16* out = (z == 0) ? q_ws : (z == 1) ? k_ws : vt_ws;
    gemm_body<128, false>(A, W, bias, out, (z == 2) ? 1 : 0);
}

__global__ __launch_bounds__(256) void proj_out(
    const u16* __restrict__ A, const u16* __restrict__ Wpb,
    const float* __restrict__ bp, float* __restrict__ y) {
    gemm_body<64, true>(A, Wpb, bp, y, 2);
}

// ---------------------------------------------------------------------------
// attn_fused v3: 4-wave block per (bh, 16-row strip). 1D grid 2048, bijective
// XCD swizzle (4 contiguous bh per XCD -> K/V L2-resident; big strips first).
// Pass 1: per tile QK^T -> E (c[4] only, 16 VGPR) -> P = bf16(E) UNNORMALIZED
// -> PV MFMA immediately; accumulate row sums. O is linear in P, so normalize
// once at the end: Osum = o * rl. Pass 2: recompute QK^T + exp (cheap,
// latency-bound regime) and write a = E*rl with nontemporal stores. Frees
// ~48 VGPR vs v2 -> ~2x occupancy for latency hiding.
// ---------------------------------------------------------------------------
__global__ __launch_bounds__(256) void attn_fused(
    const u16* __restrict__ q_ws, const u16* __restrict__ k_ws,
    const u16* __restrict__ vt_ws, float* __restrict__ a_out,
    u16* __restrict__ ao_ws) {
    __shared__ u16 P[4][1024];        // per-wave blocked [kseg(8)][m(16)][8] = 2 KB each
    __shared__ float Ls[4][16];       // per-wave partial row sums
    __shared__ float Osum[4][1024];   // per-wave partial O (normalized), xor-swizzled

    const int tid = threadIdx.x;
    const int wave = tid >> 6, lane = tid & 63;
    const int quad = lane >> 4, l16 = lane & 15;

    // bijective XCD swizzle: 2048 blocks, 8 XCDs, 256 per XCD -> 4 bh per XCD.
    const int id = blockIdx.x;
    const int wgid = (id & 7) * 256 + (id >> 3);
    const int bh = wgid >> 6;
    const int strip = 63 - (wgid & 63);   // big strips first within each bh
    const int b = bh >> 4, h = bh & 15;
    const int wrow = strip * 16;
    const int nt = (strip >> 2) + 1;

    const u16* qh = q_ws + (size_t)bh * 65536;
    const u16* kh = k_ws + (size_t)bh * 65536;
    const u16* vh = vt_ws + (size_t)bh * 65536;
    float* ah = a_out + ((size_t)bh << 20);

    bf16x8 qf[2];
    qf[0] = *(const bf16x8*)(qh + (size_t)(wrow + l16) * 64 + quad * 8);
    qf[1] = *(const bf16x8*)(qh + (size_t)(wrow + l16) * 64 + 32 + quad * 8);

    float sum_r[4] = {0.f, 0.f, 0.f, 0.f};
    f32x4 o[4] = {};

    // ---- pass 1: QK^T -> E -> P(unnorm bf16) -> PV; row sums ----
    for (int s = 0; s < 4; ++s) {
        const int ct = wave + s * 4;
        if (ct < nt) {
            f32x4 c[4] = {};
#pragma unroll
            for (int ks = 0; ks < 2; ++ks)
#pragma unroll
                for (int cb = 0; cb < 4; ++cb) {
                    bf16x8 kf = *(const bf16x8*)(kh + (size_t)(ct * 64 + cb * 16 + l16) * 64 + ks * 32 + quad * 8);
                    c[cb] = MFMA16(qf[ks], kf, c[cb]);
                }
#pragma unroll
            for (int cb = 0; cb < 4; ++cb) {
                const int s_col = cb * 16 + l16;
                const int col = ct * 64 + s_col;
#pragma unroll
                for (int r = 0; r < 4; ++r) {
                    const int m = quad * 4 + r;
                    const int trow = wrow + m;
                    float E = __expf(c[cb][r] * 0.125f - 20.0f);
                    if (col > trow) E = 0.0f;
                    sum_r[r] += E;
                    P[wave][(s_col >> 3) * 128 + m * 8 + (s_col & 7)] = f2bf(E);
                }
            }
#pragma unroll
            for (int ks = 0; ks < 2; ++ks) {
                bf16x8 pf = *(const bf16x8*)(&P[wave][(ks * 4 + quad) * 128 + l16 * 8]);
#pragma unroll
                for (int nb = 0; nb < 4; ++nb) {
                    bf16x8 vf = *(const bf16x8*)(vh + (size_t)(nb * 16 + l16) * 1024 + ct * 64 + ks * 32 + quad * 8);
                    o[nb] = MFMA16(pf, vf, o[nb]);
                }
            }
        }
    }

    // reduce sums over the 16 column-lanes, then across waves via LDS
#pragma unroll
    for (int r = 0; r < 4; ++r) {
#pragma unroll
        for (int off = 1; off < 16; off <<= 1)
            sum_r[r] += __shfl_xor(sum_r[r], off);
    }
    if (l16 == 0) {
#pragma unroll
        for (int r = 0; r < 4; ++r) Ls[wave][quad * 4 + r] = sum_r[r];
    }
    __syncthreads();

    float rl[4];
#pragma unroll
    for (int r = 0; r < 4; ++r) {
        const int m = quad * 4 + r;
        rl[r] = 1.0f / (Ls[0][m] + Ls[1][m] + Ls[2][m] + Ls[3][m]);
    }

    // fold normalized partial O into LDS now (frees o for pass 2)
#pragma unroll
    for (int nb = 0; nb < 4; ++nb)
#pragma unroll
        for (int r = 0; r < 4; ++r) {
            const int row = quad * 4 + r;
            const int d = nb * 16 + l16;
            Osum[wave][row * 64 + (d ^ ((row >> 2) << 4))] = o[nb][r] * rl[r];
        }

    // ---- pass 2: recompute E, write a = E*rl (nontemporal) ----
    for (int s = 0; s < 4; ++s) {
        const int ct = wave + s * 4;
        if (ct < nt) {
            f32x4 c[4] = {};
#pragma unroll
            for (int ks = 0; ks < 2; ++ks)
#pragma unroll
                for (int cb = 0; cb < 4; ++cb) {
                    bf16x8 kf = *(const bf16x8*)(kh + (size_t)(ct * 64 + cb * 16 + l16) * 64 + ks * 32 + quad * 8);
                    c[cb] = MFMA16(qf[ks], kf, c[cb]);
                }
#pragma unroll
            for (int cb = 0; cb < 4; ++cb) {
                const int col = ct * 64 + cb * 16 + l16;
#pragma unroll
                for (int r = 0; r < 4; ++r) {
                    const int trow = wrow + quad * 4 + r;
                    float E = __expf(c[cb][r] * 0.125f - 20.0f);
                    if (col > trow) E = 0.0f;
                    __builtin_nontemporal_store(E * rl[r], ah + (size_t)trow * 1024 + col);
                }
            }
        }
    }

    // zero the fully-masked upper tiles (nontemporal, vectorized)
    {
        const f32x4 zz = {0.f, 0.f, 0.f, 0.f};
        for (int ct = nt + wave; ct < 16; ct += 4) {
#pragma unroll
            for (int j = 0; j < 4; ++j)
                __builtin_nontemporal_store(
                    zz, (f32x4*)(ah + (size_t)(wrow + j * 4 + quad) * 1024 + ct * 64 + l16 * 4));
        }
    }

    __syncthreads();

    // ---- reduce partial O across waves, write ao (bf16) ----
#pragma unroll
    for (int i = 0; i < 4; ++i) {
        const int e = tid + i * 256;
        const int row = e >> 6, d = e & 63;
        const int sd = row * 64 + (d ^ ((row >> 2) << 4));
        const float v = Osum[0][sd] + Osum[1][sd] + Osum[2][sd] + Osum[3][sd];
        ao_ws[((size_t)(b * 1024 + wrow + row)) * 1024 + h * 64 + d] = f2bf(v);
    }
}

// ---------------------------------------------------------------------------
extern "C" void kernel_launch(void* const* d_in, const int* in_sizes, int n_in,
                              void* d_out, int out_size, void* d_ws, size_t ws_size,
                              hipStream_t stream) {
    const float* Q  = (const float*)d_in[0];
    const float* K  = (const float*)d_in[1];
    const float* V  = (const float*)d_in[2];
    const float* Wq = (const float*)d_in[3];
    const float* bq = (const float*)d_in[4];
    const float* Wk = (const float*)d_in[5];
    const float* bk = (const float*)d_in[6];
    const float* Wv = (const float*)d_in[7];
    const float* bv = (const float*)d_in[8];
    const float* Wp = (const float*)d_in[9];
    const float* bp = (const float*)d_in[10];
    // d_in[11] = attn_mask (static causal) -- unused

    float* y = (float*)d_out;                    // [B,T,C] fp32
    float* a = y + (size_t)2 * 1024 * 1024;      // [B,H,T,T] fp32

    const size_t M1 = (size_t)1 << 20;
    u16* q_ws  = (u16*)d_ws;
    u16* k_ws  = q_ws  + 2 * M1;
    u16* vt_ws = k_ws  + 2 * M1;
    u16* ao_ws = vt_ws + 2 * M1;
    u16* Qb    = ao_ws + 2 * M1;
    u16* Kb    = Qb    + 2 * M1;
    u16* Vb    = Kb    + 2 * M1;
    u16* Wqb   = Vb    + 2 * M1;
    u16* Wkb   = Wqb   + M1;
    u16* Wvb   = Wkb   + M1;
    u16* Wpb   = Wvb   + M1;

    hipLaunchKernelGGL(cvt_bf16, dim3(1024, 7), dim3(256), 0, stream,
                       Q, K, V, Wq, Wk, Wv, Wp, Qb, Kb, Vb, Wqb, Wkb, Wvb, Wpb);
    hipLaunchKernelGGL(proj_qkv, dim3(16, 16, 3), dim3(256), 0, stream,
                       Qb, Kb, Vb, Wqb, Wkb, Wvb, bq, bk, bv, q_ws, k_ws, vt_ws);
    hipLaunchKernelGGL(attn_fused, dim3(2048), dim3(256), 0, stream,
                       q_ws, k_ws, vt_ws, a, ao_ws);
    hipLaunchKernelGGL(proj_out, dim3(16, 32, 1), dim3(256), 0, stream,
                       ao_ws, Wpb, bp, y);
}

// Round 5
// 260.084 us; speedup vs baseline: 1.0590x; 1.0590x over previous
//
#include <hip/hip_runtime.h>
#include <hip/hip_bf16.h>

typedef short bf16x8 __attribute__((ext_vector_type(8)));
typedef float f32x4 __attribute__((ext_vector_type(4)));
typedef unsigned short u16;
typedef u16 u16x8 __attribute__((ext_vector_type(8)));

#define MFMA16(a, b, c) __builtin_amdgcn_mfma_f32_16x16x32_bf16(a, b, c, 0, 0, 0)

// B=2, T=1024, C=1024, H=16, HD=64.
// Inputs fp32; outputs fp32: y [2M], a [32M].
// d_ws (u16 elems): q[2M] k[2M] vt[2M] ao[2M] Qb[2M] Kb[2M] Vb[2M]
//                   Wqb[1M] Wkb[1M] Wvb[1M] Wpb[1M]  = 18M u16 = 36 MB.

__device__ __forceinline__ u16 f2bf(float f) {
    unsigned u = __builtin_bit_cast(unsigned, f);
    unsigned r = (u + 0x7FFFu + ((u >> 16) & 1u)) >> 16;
    return (u16)r;
}

// ---------------------------------------------------------------------------
// cvt_bf16 prepass: fp32 -> bf16 (RNE) for all GEMM operands, once.
// grid (1024, 7); z: 0=Q 1=K 2=V 3=Wq 4=Wk 5=Wv 6=Wp.
// ---------------------------------------------------------------------------
__global__ __launch_bounds__(256) void cvt_bf16(
    const float* __restrict__ Q, const float* __restrict__ K, const float* __restrict__ V,
    const float* __restrict__ Wq, const float* __restrict__ Wk, const float* __restrict__ Wv,
    const float* __restrict__ Wp,
    u16* __restrict__ Qb, u16* __restrict__ Kb, u16* __restrict__ Vb,
    u16* __restrict__ Wqb, u16* __restrict__ Wkb, u16* __restrict__ Wvb,
    u16* __restrict__ Wpb) {
    const int z = blockIdx.y;
    const float* src;
    u16* dst;
    int n;
    switch (z) {
        case 0: src = Q;  dst = Qb;  n = 1 << 21; break;
        case 1: src = K;  dst = Kb;  n = 1 << 21; break;
        case 2: src = V;  dst = Vb;  n = 1 << 21; break;
        case 3: src = Wq; dst = Wqb; n = 1 << 20; break;
        case 4: src = Wk; dst = Wkb; n = 1 << 20; break;
        case 5: src = Wv; dst = Wvb; n = 1 << 20; break;
        default: src = Wp; dst = Wpb; n = 1 << 20; break;
    }
    const int i = (blockIdx.x * 256 + threadIdx.x) * 8;
    if (i >= n) return;
    float4 f0 = *(const float4*)(src + i);
    float4 f1 = *(const float4*)(src + i + 4);
    u16x8 t;
    t[0] = f2bf(f0.x); t[1] = f2bf(f0.y); t[2] = f2bf(f0.z); t[3] = f2bf(f0.w);
    t[4] = f2bf(f1.x); t[5] = f2bf(f1.y); t[6] = f2bf(f1.z); t[7] = f2bf(f1.w);
    *(u16x8*)(dst + i) = t;
}

// ---------------------------------------------------------------------------
// m97-style bt-GEMM: out = A(Mx1024) @ W(1024x1024)^T + bias.
// Linear LDS [row][64], staged via global_load_lds width=16 (no VALU staging).
// BM x 64 tile, BK=64, 4 waves. BM=128 for proj_qkv, BM=64 for proj_out.
// mode 0: [b,h,t,d]; mode 1: [b,h,d,t]; mode 2: row-major (fp32 y).
// ---------------------------------------------------------------------------
template <int BM, bool OF32>
__device__ inline void gemm_body(const u16* __restrict__ A,
                                 const u16* __restrict__ W,
                                 const float* __restrict__ bias,
                                 void* __restrict__ outp, int mode) {
    __shared__ u16 As[BM * 64];   // [row][64] linear
    __shared__ u16 Bs[64 * 64];   // [row][64] linear

    const int tid = threadIdx.x;
    const int wave = tid >> 6, lane = tid & 63;
    const int quad = lane >> 4, l16 = lane & 15;
    constexpr int WM = BM / 2;    // wave tile rows
    constexpr int MI = WM / 16;   // m-frags per wave
    const int wm = (wave >> 1) * WM;
    const int wn = (wave & 1) * 32;
    const int m0 = blockIdx.y * BM;
    const int n0 = blockIdx.x * 64;

    f32x4 acc[MI][2] = {};

    const int lrow = lane >> 3;
    const int lseg = lane & 7;
    const u16* Ag = A + (size_t)(m0 + wave * 8 + lrow) * 1024 + lseg * 8;
    const u16* Wg = W + (size_t)(n0 + wave * 8 + lrow) * 1024 + lseg * 8;
    u16* AsBase = As + wave * 8 * 64;
    u16* BsBase = Bs + wave * 8 * 64;

    for (int kt = 0; kt < 16; ++kt) {
        const int k0 = kt * 64;
        __syncthreads();
#pragma unroll
        for (int rr = 0; rr < BM / 32; ++rr)
            __builtin_amdgcn_global_load_lds(
                (const __attribute__((address_space(1))) void*)(Ag + (size_t)rr * 32 * 1024 + k0),
                (__attribute__((address_space(3))) void*)(AsBase + rr * 32 * 64), 16, 0, 0);
#pragma unroll
        for (int rr = 0; rr < 2; ++rr)
            __builtin_amdgcn_global_load_lds(
                (const __attribute__((address_space(1))) void*)(Wg + (size_t)rr * 32 * 1024 + k0),
                (__attribute__((address_space(3))) void*)(BsBase + rr * 32 * 64), 16, 0, 0);
        __syncthreads();
#pragma unroll
        for (int ks = 0; ks < 2; ++ks) {
            bf16x8 af[MI], bfr[2];
#pragma unroll
            for (int mi = 0; mi < MI; ++mi)
                af[mi] = *(const bf16x8*)(As + (wm + mi * 16 + l16) * 64 + ks * 32 + quad * 8);
#pragma unroll
            for (int ni = 0; ni < 2; ++ni)
                bfr[ni] = *(const bf16x8*)(Bs + (wn + ni * 16 + l16) * 64 + ks * 32 + quad * 8);
#pragma unroll
            for (int mi = 0; mi < MI; ++mi)
#pragma unroll
                for (int ni = 0; ni < 2; ++ni)
                    acc[mi][ni] = MFMA16(af[mi], bfr[ni], acc[mi][ni]);
        }
    }

#pragma unroll
    for (int ni = 0; ni < 2; ++ni) {
        const int n = n0 + wn + ni * 16 + l16;
        const float bv = bias[n];
#pragma unroll
        for (int mi = 0; mi < MI; ++mi) {
#pragma unroll
            for (int r = 0; r < 4; ++r) {
                const int m = m0 + wm + mi * 16 + quad * 4 + r;
                const float val = acc[mi][ni][r] + bv;
                size_t idx;
                if (mode == 0) {
                    int b = m >> 10, t = m & 1023, h = n >> 6, d = n & 63;
                    idx = ((size_t)((b * 16 + h) * 1024 + t)) * 64 + d;
                } else if (mode == 1) {
                    int b = m >> 10, t = m & 1023, h = n >> 6, d = n & 63;
                    idx = ((size_t)((b * 16 + h) * 64 + d)) * 1024 + t;
                } else {
                    idx = (size_t)m * 1024 + n;
                }
                if (OF32) ((float*)outp)[idx] = val;
                else      ((u16*)outp)[idx] = f2bf(val);
            }
        }
    }
}

__global__ __launch_bounds__(256) void proj_qkv(
    const u16* __restrict__ Qb, const u16* __restrict__ Kb, const u16* __restrict__ Vb,
    const u16* __restrict__ Wqb, const u16* __restrict__ Wkb, const u16* __restrict__ Wvb,
    const float* __restrict__ bq, const float* __restrict__ bk, const float* __restrict__ bv,
    u16* __restrict__ q_ws, u16* __restrict__ k_ws, u16* __restrict__ vt_ws) {
    const int z = blockIdx.z;
    const u16* A = (z == 0) ? Qb : (z == 1) ? Kb : Vb;
    const u16* W = (z == 0) ? Wqb : (z == 1) ? Wkb : Wvb;
    const float* bias = (z == 0) ? bq : (z == 1) ? bk : bv;
    u16* out = (z == 0) ? q_ws : (z == 1) ? k_ws : vt_ws;
    gemm_body<128, false>(A, W, bias, out, (z == 2) ? 1 : 0);
}

__global__ __launch_bounds__(256) void proj_out(
    const u16* __restrict__ A, const u16* __restrict__ Wpb,
    const float* __restrict__ bp, float* __restrict__ y) {
    gemm_body<64, true>(A, Wpb, bp, y, 2);
}

// ---------------------------------------------------------------------------
// attn_fused v4: 4-wave block per (bh, 16-row strip). 1D grid 2048, bijective
// XCD swizzle (4 contiguous bh per XCD -> K/V L2-resident; big strips first).
// Pass 1 (single QK pass, v2-style): QK^T -> E kept in regs (c[4][4], 64 VGPR)
// + per-lane partial row sums. Cross-wave LDS reduce -> rl. Pass 2: normalized
// v = E*rl routed through per-wave LDS scratch (reusing Osum slice, idle until
// epilogue) -> coalesced f32x4 nontemporal a-stores (4 VMEM instr/lane/tile
// instead of 16 scalar); normalized P -> PV MFMA. Epilogue: fold o into Osum,
// cross-wave sum, ao (bf16). No recompute (v3's mistake reverted).
// ---------------------------------------------------------------------------
__global__ __launch_bounds__(256) void attn_fused(
    const u16* __restrict__ q_ws, const u16* __restrict__ k_ws,
    const u16* __restrict__ vt_ws, float* __restrict__ a_out,
    u16* __restrict__ ao_ws) {
    __shared__ u16 P[4][1024];        // per-wave blocked [kseg(8)][m(16)][8] = 2 KB each
    __shared__ float Ls[4][16];       // per-wave partial row sums
    __shared__ float Osum[4][1024];   // per-wave [16][64]: a-transpose scratch, then O partials

    const int tid = threadIdx.x;
    const int wave = tid >> 6, lane = tid & 63;
    const int quad = lane >> 4, l16 = lane & 15;

    // bijective XCD swizzle: 2048 blocks, 8 XCDs, 256 per XCD -> 4 bh per XCD.
    const int id = blockIdx.x;
    const int wgid = (id & 7) * 256 + (id >> 3);
    const int bh = wgid >> 6;
    const int strip = 63 - (wgid & 63);   // big strips first within each bh
    const int b = bh >> 4, h = bh & 15;
    const int wrow = strip * 16;
    const int nt = (strip >> 2) + 1;

    const u16* qh = q_ws + (size_t)bh * 65536;
    const u16* kh = k_ws + (size_t)bh * 65536;
    const u16* vh = vt_ws + (size_t)bh * 65536;
    float* ah = a_out + ((size_t)bh << 20);

    bf16x8 qf[2];
    qf[0] = *(const bf16x8*)(qh + (size_t)(wrow + l16) * 64 + quad * 8);
    qf[1] = *(const bf16x8*)(qh + (size_t)(wrow + l16) * 64 + 32 + quad * 8);

    // ---- pass 1: QK^T -> E (kept in regs), partial row sums ----
    f32x4 c[4][4] = {};
    float sum_r[4] = {0.f, 0.f, 0.f, 0.f};

#pragma unroll
    for (int s = 0; s < 4; ++s) {
        const int ct = wave + s * 4;
        if (ct < nt) {
#pragma unroll
            for (int ks = 0; ks < 2; ++ks)
#pragma unroll
                for (int cb = 0; cb < 4; ++cb) {
                    bf16x8 kf = *(const bf16x8*)(kh + (size_t)(ct * 64 + cb * 16 + l16) * 64 + ks * 32 + quad * 8);
                    c[s][cb] = MFMA16(qf[ks], kf, c[s][cb]);
                }
#pragma unroll
            for (int cb = 0; cb < 4; ++cb) {
                const int col = ct * 64 + cb * 16 + l16;
#pragma unroll
                for (int r = 0; r < 4; ++r) {
                    const int trow = wrow + quad * 4 + r;
                    float E = __expf(c[s][cb][r] * 0.125f - 20.0f);
                    if (col > trow) E = 0.0f;
                    c[s][cb][r] = E;
                    sum_r[r] += E;
                }
            }
        }
    }

    // zero the fully-masked upper tiles (nontemporal, vectorized)
    {
        const f32x4 zz = {0.f, 0.f, 0.f, 0.f};
        for (int ct = nt + wave; ct < 16; ct += 4) {
#pragma unroll
            for (int j = 0; j < 4; ++j)
                __builtin_nontemporal_store(
                    zz, (f32x4*)(ah + (size_t)(wrow + j * 4 + quad) * 1024 + ct * 64 + l16 * 4));
        }
    }

    // reduce sums over the 16 column-lanes, then across waves via LDS
#pragma unroll
    for (int r = 0; r < 4; ++r) {
#pragma unroll
        for (int off = 1; off < 16; off <<= 1)
            sum_r[r] += __shfl_xor(sum_r[r], off);
    }
    if (l16 == 0) {
#pragma unroll
        for (int r = 0; r < 4; ++r) Ls[wave][quad * 4 + r] = sum_r[r];
    }
    __syncthreads();

    float rl[4];
#pragma unroll
    for (int r = 0; r < 4; ++r) {
        const int m = quad * 4 + r;
        rl[r] = 1.0f / (Ls[0][m] + Ls[1][m] + Ls[2][m] + Ls[3][m]);
    }

    // ---- pass 2: normalized a via LDS transpose -> f32x4 NT stores; PV ----
    float* scratch = &Osum[wave][0];  // per-wave [16][64] f32, wave-private
    f32x4 o[4] = {};
#pragma unroll
    for (int s = 0; s < 4; ++s) {
        const int ct = wave + s * 4;
        if (ct < nt) {
#pragma unroll
            for (int cb = 0; cb < 4; ++cb) {
                const int s_col = cb * 16 + l16;
#pragma unroll
                for (int r = 0; r < 4; ++r) {
                    const int m = quad * 4 + r;
                    const float v = c[s][cb][r] * rl[r];
                    scratch[m * 64 + s_col] = v;
                    P[wave][(s_col >> 3) * 128 + m * 8 + (s_col & 7)] = f2bf(v);
                }
            }
            // coalesced NT store: lane covers row (lane>>4)+4i, 4 cols
            {
                const int col4 = (lane & 15) * 4;
#pragma unroll
                for (int i = 0; i < 4; ++i) {
                    const int row = (lane >> 4) + i * 4;
                    f32x4 vv = *(const f32x4*)(scratch + row * 64 + col4);
                    __builtin_nontemporal_store(
                        vv, (f32x4*)(ah + (size_t)(wrow + row) * 1024 + ct * 64 + col4));
                }
            }
#pragma unroll
            for (int ks = 0; ks < 2; ++ks) {
                bf16x8 pf = *(const bf16x8*)(&P[wave][(ks * 4 + quad) * 128 + l16 * 8]);
#pragma unroll
                for (int nb = 0; nb < 4; ++nb) {
                    bf16x8 vf = *(const bf16x8*)(vh + (size_t)(nb * 16 + l16) * 1024 + ct * 64 + ks * 32 + quad * 8);
                    o[nb] = MFMA16(pf, vf, o[nb]);
                }
            }
        }
    }

    // ---- fold o (already normalized, P was normalized) into Osum ----
    __syncthreads();  // all waves done using their scratch slice
#pragma unroll
    for (int nb = 0; nb < 4; ++nb)
#pragma unroll
        for (int r = 0; r < 4; ++r) {
            const int row = quad * 4 + r;
            const int d = nb * 16 + l16;
            Osum[wave][row * 64 + (d ^ ((row >> 2) << 4))] = o[nb][r];
        }
    __syncthreads();

    // ---- reduce partial O across waves, write ao (bf16) ----
#pragma unroll
    for (int i = 0; i < 4; ++i) {
        const int e = tid + i * 256;
        const int row = e >> 6, d = e & 63;
        const int sd = row * 64 + (d ^ ((row >> 2) << 4));
        const float v = Osum[0][sd] + Osum[1][sd] + Osum[2][sd] + Osum[3][sd];
        ao_ws[((size_t)(b * 1024 + wrow + row)) * 1024 + h * 64 + d] = f2bf(v);
    }
}

// ---------------------------------------------------------------------------
extern "C" void kernel_launch(void* const* d_in, const int* in_sizes, int n_in,
                              void* d_out, int out_size, void* d_ws, size_t ws_size,
                              hipStream_t stream) {
    const float* Q  = (const float*)d_in[0];
    const float* K  = (const float*)d_in[1];
    const float* V  = (const float*)d_in[2];
    const float* Wq = (const float*)d_in[3];
    const float* bq = (const float*)d_in[4];
    const float* Wk = (const float*)d_in[5];
    const float* bk = (const float*)d_in[6];
    const float* Wv = (const float*)d_in[7];
    const float* bv = (const float*)d_in[8];
    const float* Wp = (const float*)d_in[9];
    const float* bp = (const float*)d_in[10];
    // d_in[11] = attn_mask (static causal) -- unused

    float* y = (float*)d_out;                    // [B,T,C] fp32
    float* a = y + (size_t)2 * 1024 * 1024;      // [B,H,T,T] fp32

    const size_t M1 = (size_t)1 << 20;
    u16* q_ws  = (u16*)d_ws;
    u16* k_ws  = q_ws  + 2 * M1;
    u16* vt_ws = k_ws  + 2 * M1;
    u16* ao_ws = vt_ws + 2 * M1;
    u16* Qb    = ao_ws + 2 * M1;
    u16* Kb    = Qb    + 2 * M1;
    u16* Vb    = Kb    + 2 * M1;
    u16* Wqb   = Vb    + 2 * M1;
    u16* Wkb   = Wqb   + M1;
    u16* Wvb   = Wkb   + M1;
    u16* Wpb   = Wvb   + M1;

    hipLaunchKernelGGL(cvt_bf16, dim3(1024, 7), dim3(256), 0, stream,
                       Q, K, V, Wq, Wk, Wv, Wp, Qb, Kb, Vb, Wqb, Wkb, Wvb, Wpb);
    hipLaunchKernelGGL(proj_qkv, dim3(16, 16, 3), dim3(256), 0, stream,
                       Qb, Kb, Vb, Wqb, Wkb, Wvb, bq, bk, bv, q_ws, k_ws, vt_ws);
    hipLaunchKernelGGL(attn_fused, dim3(2048), dim3(256), 0, stream,
                       q_ws, k_ws, vt_ws, a, ao_ws);
    hipLaunchKernelGGL(proj_out, dim3(16, 32, 1), dim3(256), 0, stream,
                       ao_ws, Wpb, bp, y);
}